// Round 18
// baseline (142.948 us; speedup 1.0000x reference)
//
#include <hip/hip_runtime.h>
#include <hip/hip_bf16.h>

// Problem constants
#define B_    8
#define N_    1024
#define D_    768
#define H_    12
#define HD_   64
#define TRIPLE 2304   // 3*768
#define M_    8192    // B_*N_

typedef __attribute__((ext_vector_type(8))) short bf16x8;
typedef __attribute__((ext_vector_type(4))) float f32x4;
typedef __attribute__((ext_vector_type(2))) unsigned u32x2;
typedef __attribute__((ext_vector_type(4))) unsigned u32x4;

// f32 -> bf16 (RNE), no NaN expected in this problem
__device__ __forceinline__ unsigned short f2bf(float f) {
    union { float f; unsigned u; } v; v.f = f;
    unsigned r = v.u + 0x7fffu + ((v.u >> 16) & 1u);
    return (unsigned short)(r >> 16);
}

// packed f32x2 -> bf16x2 (lo = a, hi = b); guide-verified gfx950 instruction
__device__ __forceinline__ unsigned cvt_pk_bf16(float a, float b) {
    unsigned r;
    asm("v_cvt_pk_bf16_f32 %0, %1, %2" : "=v"(r) : "v"(a), "v"(b));
    return r;
}

// compiler-level memory fence: no instructions emitted, forbids reordering
#define COMPILER_MEM_FENCE() asm volatile("" ::: "memory")

// async 16B global->LDS (m97 pattern): LDS dest is wave-uniform base + lane*16
#define GLOAD_LDS16(gp, lp)                                                   \
    __builtin_amdgcn_global_load_lds(                                         \
        (const __attribute__((address_space(1))) void*)(gp),                  \
        (__attribute__((address_space(3))) void*)(lp), 16, 0, 0)

// ---------------- prep kernels ----------------

__global__ void k_cast_bf16(const float* __restrict__ in, unsigned short* __restrict__ out, int n4) {
    int stride = gridDim.x * blockDim.x;
    for (int i = blockIdx.x * blockDim.x + threadIdx.x; i < n4; i += stride) {
        float4 v = reinterpret_cast<const float4*>(in)[i];
        ushort4 o;
        o.x = f2bf(v.x); o.y = f2bf(v.y); o.z = f2bf(v.z); o.w = f2bf(v.w);
        reinterpret_cast<ushort4*>(out)[i] = o;
    }
}

// tiled transpose: out[c][r] = bf16(in[r][c]); in [R][C] f32. Coalesced reads
// AND writes via a padded 32x32 LDS tile. Block (32,8); grid (C/32, R/32);
// R, C are exact multiples of 32 here.  [kept: ~10us win, R13/R14]
__global__ void k_transpose_bf16(const float* __restrict__ in, unsigned short* __restrict__ out,
                                 int R, int C) {
    __shared__ float tile[32][33];
    const int tx = threadIdx.x, ty = threadIdx.y;
    const int bx = blockIdx.x * 32, by = blockIdx.y * 32;
    #pragma unroll
    for (int j = 0; j < 32; j += 8)
        tile[ty + j][tx] = in[(size_t)(by + ty + j) * C + bx + tx];
    __syncthreads();
    #pragma unroll
    for (int j = 0; j < 32; j += 8)
        out[(size_t)(bx + ty + j) * R + by + tx] = f2bf(tile[tx][ty + j]);
}

// ---------------- GEMM: C = A[M,K] * BT[N,K]^T, bf16 in, f32 acc ----------------
// 128x128 tile, 256 threads (4 waves, 2x2 of 64x64), mfma_f32_16x16x32_bf16.
// m97-style staging: global_load_lds width=16 into LINEAR [128][64] LDS.
// 2-D grid, tm fastest (R13: XCD chunk-swizzle regressed; do not re-add).
// NEW (R18): ANTI-CONVOY k-rotation -- co-resident blocks have identical
// periodic phase structure and synchronize into simultaneous vmcnt drains;
// rotating each block's k0 start phase desynchronizes them so one block's
// compute covers another's drain. Pure bijection over the same K tiles;
// accumulation is commutative (fp rounding order only).
// EPI 0: scatter qkv epilogue. EPI 1: bias + f32 out (projection).
template<int EPI>
__global__ void k_gemm(const unsigned short* __restrict__ A,
                       const unsigned short* __restrict__ BT,
                       int K,
                       unsigned short* __restrict__ q_ws,
                       unsigned short* __restrict__ k_ws,
                       unsigned short* __restrict__ vt_ws,
                       const float* __restrict__ bias,
                       float* __restrict__ outf) {
    const int tm = blockIdx.x * 128;
    const int tn = blockIdx.y * 128;
    const int tid = threadIdx.x;
    const int w = tid >> 6, l = tid & 63;
    const int g = l >> 4, l16 = l & 15;
    const int wm = (w >> 1) * 64, wn = (w & 1) * 64;

    __shared__ __align__(16) unsigned short Alds[128][64];
    __shared__ __align__(16) unsigned short Blds[128][64];

    const int srow = (l >> 3);          // 0..7
    const int scol = (l & 7) * 8;       // 0..56

    f32x4 acc[4][4];
    for (int mi = 0; mi < 4; mi++)
        for (int ni = 0; ni < 4; ni++)
            acc[mi][ni] = (f32x4){0.f, 0.f, 0.f, 0.f};

    const int ksteps = K >> 6;                            // 12 here
    int krot = ((blockIdx.x >> 3) + blockIdx.y) % ksteps; // same-XCD blocks get distinct phases

    for (int kk = 0; kk < ksteps; kk++) {
        int ki0 = kk + krot; if (ki0 >= ksteps) ki0 -= ksteps;
        int k0 = ki0 << 6;
        __syncthreads();
        #pragma unroll
        for (int i = 0; i < 4; i++) {
            int r0 = (w * 4 + i) * 8;
            GLOAD_LDS16(&A[(size_t)(tm + r0 + srow) * K + k0 + scol], &Alds[r0][0]);
            GLOAD_LDS16(&BT[(size_t)(tn + r0 + srow) * K + k0 + scol], &Blds[r0][0]);
        }
        __syncthreads();

        #pragma unroll
        for (int ki = 0; ki < 2; ki++) {
            bf16x8 af[4], bfr[4];
            #pragma unroll
            for (int mi = 0; mi < 4; mi++)
                af[mi] = *reinterpret_cast<const bf16x8*>(&Alds[wm + mi * 16 + l16][ki * 32 + g * 8]);
            #pragma unroll
            for (int ni = 0; ni < 4; ni++)
                bfr[ni] = *reinterpret_cast<const bf16x8*>(&Blds[wn + ni * 16 + l16][ki * 32 + g * 8]);
            #pragma unroll
            for (int mi = 0; mi < 4; mi++)
                #pragma unroll
                for (int ni = 0; ni < 4; ni++)
                    acc[mi][ni] = __builtin_amdgcn_mfma_f32_16x16x32_bf16(af[mi], bfr[ni], acc[mi][ni], 0, 0, 0);
        }
    }

    #pragma unroll
    for (int mi = 0; mi < 4; mi++) {
        #pragma unroll
        for (int ni = 0; ni < 4; ni++) {
            #pragma unroll
            for (int r = 0; r < 4; r++) {
                float v = acc[mi][ni][r];
                int mrow = tm + wm + mi * 16 + g * 4 + r;
                int c    = tn + wn + ni * 16 + l16;
                if (EPI == 0) {
                    int which = c / 768, cc = c - which * 768;
                    int h = cc >> 6, hd = cc & 63;
                    int b = mrow >> 10, n = mrow & 1023;
                    unsigned short bv = f2bf(v);
                    if (which == 0)      q_ws[((b * H_ + h) * N_ + n) * HD_ + hd] = bv;
                    else if (which == 1) k_ws[((b * H_ + h) * N_ + n) * HD_ + hd] = bv;
                    else                 vt_ws[((b * H_ + h) * HD_ + hd) * N_ + n] = bv;
                } else {
                    outf[mrow * 768 + c] = v + bias[c];
                }
            }
        }
    }
}

// ---------------- attention: R11/R14 structure + anti-convoy kt rotation ----------------
// Structure FROZEN (R11/R13/R14/R17-passing form; pipeline variants 0/5 failed).
// NEW (R18): per-block kt rotation, rot = (f>>3)&15 -- same-XCD blocks (f%8
// const) get 16 distinct phases, desynchronizing the stage-drain convoy.
// Bijection over the 16 key-tiles; fixed-shift softmax has NO order-dependent
// running state (no max tracking), so sums commute (fp rounding order only).
__global__ void __launch_bounds__(256, 3)
k_attn(const unsigned short* __restrict__ q_ws,
       const unsigned short* __restrict__ k_ws,
       const unsigned short* __restrict__ vt_ws,
       unsigned short* __restrict__ att_ws) {
    const int f = blockIdx.x;
    const int qt = f / 96;          // 0..7
    const int bh = f - qt * 96;     // 0..95 ; f%8 == bh%8 -> XCD-local K/V
    const int b = bh / H_, h = bh - b * H_;
    const int tid = threadIdx.x;
    const int w = tid >> 6, l = tid & 63;
    const int g = l >> 4, l16 = l & 15;

    const unsigned short* Qp = q_ws + bh * N_ * HD_;
    const unsigned short* Kp = k_ws + bh * N_ * HD_;
    const unsigned short* Vt = vt_ws + bh * HD_ * N_;
    const int qrow0 = qt * 128 + w * 32;   // this wave's 32 q-rows

    __shared__ __align__(16) unsigned short Kst[64][64];
    __shared__ __align__(16) unsigned short Vst[64][64];
    __shared__ __align__(16) unsigned Plds[4][2][16][36];

    const int sr = l >> 3;          // 0..7  (row within 8-row stripe)
    const int sc = (l & 7) * 8;     // 0..56 (col chunk, elems)

    bf16x8 qf[2][2];
    #pragma unroll
    for (int qb = 0; qb < 2; qb++)
        #pragma unroll
        for (int ki = 0; ki < 2; ki++)
            qf[qb][ki] = *reinterpret_cast<const bf16x8*>(
                &Qp[(qrow0 + qb * 16 + l16) * HD_ + ki * 32 + g * 8]);

    f32x4 o[2][4];
    #pragma unroll
    for (int qb = 0; qb < 2; qb++)
        #pragma unroll
        for (int hi = 0; hi < 4; hi++) o[qb][hi] = (f32x4){0.f, 0.f, 0.f, 0.f};
    float lrow[2] = {0.f, 0.f};

    const int rot = (f >> 3) & 15;   // anti-convoy phase (distinct per same-XCD block)

    #pragma unroll 1
    for (int kt0 = 0; kt0 < 16; kt0++) {
        const int kt = (kt0 + rot) & 15;
        __syncthreads();   // all waves done reading the previous tile
        #pragma unroll
        for (int i = 0; i < 2; i++) {
            int r0 = w * 16 + i * 8;
            GLOAD_LDS16(&Kp[(size_t)(kt * 64 + r0 + sr) * HD_ + sc], &Kst[r0][0]);
            GLOAD_LDS16(&Vt[(size_t)(r0 + sr) * N_ + kt * 64 + sc], &Vst[r0][0]);
        }
        __syncthreads();   // compiler drains vmcnt(0) before s_barrier

        f32x4 st[2][4];
        #pragma unroll
        for (int qb = 0; qb < 2; qb++)
            #pragma unroll
            for (int ni = 0; ni < 4; ni++) st[qb][ni] = (f32x4){0.f, 0.f, 0.f, 0.f};
        #pragma unroll
        for (int ki = 0; ki < 2; ki++) {
            #pragma unroll
            for (int ni = 0; ni < 4; ni++) {
                bf16x8 kf = *reinterpret_cast<const bf16x8*>(
                    &Kst[ni * 16 + l16][ki * 32 + g * 8]);
                st[0][ni] = __builtin_amdgcn_mfma_f32_16x16x32_bf16(kf, qf[0][ki], st[0][ni], 0, 0, 0);
                st[1][ni] = __builtin_amdgcn_mfma_f32_16x16x32_bf16(kf, qf[1][ki], st[1][ni], 0, 0, 0);
            }
        }

        #pragma unroll
        for (int qb = 0; qb < 2; qb++) {
            #pragma unroll
            for (int ni = 0; ni < 4; ni++) {
                float p0 = __expf(st[qb][ni][0] - 12.0f);
                float p1 = __expf(st[qb][ni][1] - 12.0f);
                float p2 = __expf(st[qb][ni][2] - 12.0f);
                float p3 = __expf(st[qb][ni][3] - 12.0f);
                lrow[qb] += (p0 + p1) + (p2 + p3);
                u32x2 pk = (u32x2){cvt_pk_bf16(p0, p1), cvt_pk_bf16(p2, p3)};
                *reinterpret_cast<u32x2*>(&Plds[w][qb][l16][ni * 8 + g * 2]) = pk;
            }
        }

        COMPILER_MEM_FENCE();   // P writes may not sink below the PV reads

        #pragma unroll
        for (int ki2 = 0; ki2 < 2; ki2++) {
            bf16x8 vf[4];
            #pragma unroll
            for (int hi = 0; hi < 4; hi++)
                vf[hi] = *reinterpret_cast<const bf16x8*>(
                    &Vst[hi * 16 + l16][ki2 * 32 + g * 8]);
            #pragma unroll
            for (int qb = 0; qb < 2; qb++) {
                u32x4 praw = *reinterpret_cast<const u32x4*>(
                    &Plds[w][qb][l16][ki2 * 16 + g * 4]);
                bf16x8 pa = __builtin_bit_cast(bf16x8, praw);
                #pragma unroll
                for (int hi = 0; hi < 4; hi++)
                    o[qb][hi] = __builtin_amdgcn_mfma_f32_16x16x32_bf16(pa, vf[hi], o[qb][hi], 0, 0, 0);
            }
        }

        COMPILER_MEM_FENCE();   // next tile's P writes may not hoist above these reads
    }

    #pragma unroll
    for (int qb = 0; qb < 2; qb++) {
        float s0 = lrow[qb];
        s0 += __shfl_xor(s0, 16);
        s0 += __shfl_xor(s0, 32);
        lrow[qb] = s0;
    }

    #pragma unroll
    for (int qb = 0; qb < 2; qb++) {
        float inv[4];
        #pragma unroll
        for (int r = 0; r < 4; r++)
            inv[r] = 8.0f / __shfl(lrow[qb], g * 4 + r);   // *8: softmax/SCALE quirk
        #pragma unroll
        for (int hi = 0; hi < 4; hi++) {
            #pragma unroll
            for (int r = 0; r < 4; r++) {
                float v = o[qb][hi][r] * inv[r];
                int n = qrow0 + qb * 16 + g * 4 + r;
                att_ws[((size_t)(b * N_ + n)) * 768 + h * 64 + hi * 16 + l16] = f2bf(v);
            }
        }
    }
}

// ---------------- launch ----------------

extern "C" void kernel_launch(void* const* d_in, const int* in_sizes, int n_in,
                              void* d_out, int out_size, void* d_ws, size_t ws_size,
                              hipStream_t stream) {
    const float* x      = (const float*)d_in[0];
    const float* w_qkv  = (const float*)d_in[1];
    const float* w_proj = (const float*)d_in[2];
    const float* b_proj = (const float*)d_in[3];
    float* out = (float*)d_out;

    char* ws = (char*)d_ws;
    size_t off = 0;
    auto carve = [&](size_t bytes) {
        void* p = ws + off;
        off += (bytes + 255) & ~(size_t)255;
        return p;
    };
    unsigned short* xb     = (unsigned short*)carve((size_t)M_ * D_ * 2);
    unsigned short* wqkvT  = (unsigned short*)carve((size_t)TRIPLE * D_ * 2);
    unsigned short* wprojT = (unsigned short*)carve((size_t)D_ * D_ * 2);
    unsigned short* q_ws   = (unsigned short*)carve((size_t)B_ * H_ * N_ * HD_ * 2);
    unsigned short* k_ws   = (unsigned short*)carve((size_t)B_ * H_ * N_ * HD_ * 2);
    unsigned short* vt_ws  = (unsigned short*)carve((size_t)B_ * H_ * N_ * HD_ * 2);
    unsigned short* att_ws = (unsigned short*)carve((size_t)M_ * 768 * 2);

    k_cast_bf16<<<2048, 256, 0, stream>>>(x, xb, M_ * D_ / 4);
    // tiled transposes: in [R][C] -> out [C][R]; grid (C/32, R/32), block (32,8)
    k_transpose_bf16<<<dim3(TRIPLE / 32, D_ / 32), dim3(32, 8), 0, stream>>>(w_qkv, wqkvT, D_, TRIPLE);
    k_transpose_bf16<<<dim3(D_ / 32, D_ / 32), dim3(32, 8), 0, stream>>>(w_proj, wprojT, D_, D_);

    // qkv = x @ w_qkv  -> scatter q,k,[v^T]   (2-D grid, tm fastest)
    k_gemm<0><<<dim3(M_ / 128, TRIPLE / 128), 256, 0, stream>>>(
        xb, wqkvT, D_, q_ws, k_ws, vt_ws, nullptr, nullptr);

    // attention (1-D grid; bh fastest for XCD-local K/V)
    k_attn<<<dim3(768), 256, 0, stream>>>(q_ws, k_ws, vt_ws, att_ws);

    // out = att @ w_proj + b   (2-D grid)
    k_gemm<1><<<dim3(M_ / 128, 768 / 128), 256, 0, stream>>>(
        att_ws, wprojT, D_, nullptr, nullptr, nullptr, b_proj, out);
}

// Round 19
// 135.411 us; speedup vs baseline: 1.0557x; 1.0557x over previous
//
#include <hip/hip_runtime.h>
#include <hip/hip_bf16.h>

// Problem constants
#define B_    8
#define N_    1024
#define D_    768
#define H_    12
#define HD_   64
#define TRIPLE 2304   // 3*768
#define M_    8192    // B_*N_

typedef __attribute__((ext_vector_type(8))) short bf16x8;
typedef __attribute__((ext_vector_type(4))) float f32x4;
typedef __attribute__((ext_vector_type(2))) unsigned u32x2;
typedef __attribute__((ext_vector_type(4))) unsigned u32x4;

// f32 -> bf16 (RNE), no NaN expected in this problem
__device__ __forceinline__ unsigned short f2bf(float f) {
    union { float f; unsigned u; } v; v.f = f;
    unsigned r = v.u + 0x7fffu + ((v.u >> 16) & 1u);
    return (unsigned short)(r >> 16);
}

// packed f32x2 -> bf16x2 (lo = a, hi = b); guide-verified gfx950 instruction
__device__ __forceinline__ unsigned cvt_pk_bf16(float a, float b) {
    unsigned r;
    asm("v_cvt_pk_bf16_f32 %0, %1, %2" : "=v"(r) : "v"(a), "v"(b));
    return r;
}

// compiler-level memory fence: no instructions emitted, forbids reordering
#define COMPILER_MEM_FENCE() asm volatile("" ::: "memory")

// async 16B global->LDS (m97 pattern): LDS dest is wave-uniform base + lane*16
#define GLOAD_LDS16(gp, lp)                                                   \
    __builtin_amdgcn_global_load_lds(                                         \
        (const __attribute__((address_space(1))) void*)(gp),                  \
        (__attribute__((address_space(3))) void*)(lp), 16, 0, 0)

// ---------------- prep kernels ----------------

__global__ void k_cast_bf16(const float* __restrict__ in, unsigned short* __restrict__ out, int n4) {
    int stride = gridDim.x * blockDim.x;
    for (int i = blockIdx.x * blockDim.x + threadIdx.x; i < n4; i += stride) {
        float4 v = reinterpret_cast<const float4*>(in)[i];
        ushort4 o;
        o.x = f2bf(v.x); o.y = f2bf(v.y); o.z = f2bf(v.z); o.w = f2bf(v.w);
        reinterpret_cast<ushort4*>(out)[i] = o;
    }
}

// tiled transpose: out[c][r] = bf16(in[r][c]); in [R][C] f32. Coalesced reads
// AND writes via a padded 32x32 LDS tile. Block (32,8); grid (C/32, R/32);
// R, C are exact multiples of 32 here.  [kept: ~10us win, R13/R14]
__global__ void k_transpose_bf16(const float* __restrict__ in, unsigned short* __restrict__ out,
                                 int R, int C) {
    __shared__ float tile[32][33];
    const int tx = threadIdx.x, ty = threadIdx.y;
    const int bx = blockIdx.x * 32, by = blockIdx.y * 32;
    #pragma unroll
    for (int j = 0; j < 32; j += 8)
        tile[ty + j][tx] = in[(size_t)(by + ty + j) * C + bx + tx];
    __syncthreads();
    #pragma unroll
    for (int j = 0; j < 32; j += 8)
        out[(size_t)(bx + ty + j) * R + by + tx] = f2bf(tile[tx][ty + j]);
}

// ---------------- GEMM: C = A[M,K] * BT[N,K]^T, bf16 in, f32 acc ----------------
// 128x128 tile, 256 threads (4 waves, 2x2 of 64x64), mfma_f32_16x16x32_bf16.
// m97-style staging: global_load_lds width=16 into LINEAR [128][64] LDS.
// 2-D grid, tm fastest, IN-ORDER k sweep. Measured order-perturbation record:
//   R13 XCD chunk-swizzle: FETCH 25.9->77.5MB, 62->81us (concurrent disjoint
//     tn-groups defeat L3 absorption of A re-reads). REVERTED.
//   R18 anti-convoy k-rotation: FETCH 25.9->64.9MB, 62->70.7us (concurrent
//     disjoint k-slices inflate live working set 12x). REVERTED.
// Rule: at this problem size, temporal phase-alignment across blocks IS the
// cache locality. Do not perturb block/k ordering.
// EPI 0: scatter qkv epilogue. EPI 1: bias + f32 out (projection).
template<int EPI>
__global__ void k_gemm(const unsigned short* __restrict__ A,
                       const unsigned short* __restrict__ BT,
                       int K,
                       unsigned short* __restrict__ q_ws,
                       unsigned short* __restrict__ k_ws,
                       unsigned short* __restrict__ vt_ws,
                       const float* __restrict__ bias,
                       float* __restrict__ outf) {
    const int tm = blockIdx.x * 128;
    const int tn = blockIdx.y * 128;
    const int tid = threadIdx.x;
    const int w = tid >> 6, l = tid & 63;
    const int g = l >> 4, l16 = l & 15;
    const int wm = (w >> 1) * 64, wn = (w & 1) * 64;

    __shared__ __align__(16) unsigned short Alds[128][64];
    __shared__ __align__(16) unsigned short Blds[128][64];

    const int srow = (l >> 3);          // 0..7
    const int scol = (l & 7) * 8;       // 0..56

    f32x4 acc[4][4];
    for (int mi = 0; mi < 4; mi++)
        for (int ni = 0; ni < 4; ni++)
            acc[mi][ni] = (f32x4){0.f, 0.f, 0.f, 0.f};

    for (int k0 = 0; k0 < K; k0 += 64) {
        __syncthreads();
        #pragma unroll
        for (int i = 0; i < 4; i++) {
            int r0 = (w * 4 + i) * 8;
            GLOAD_LDS16(&A[(size_t)(tm + r0 + srow) * K + k0 + scol], &Alds[r0][0]);
            GLOAD_LDS16(&BT[(size_t)(tn + r0 + srow) * K + k0 + scol], &Blds[r0][0]);
        }
        __syncthreads();

        #pragma unroll
        for (int ki = 0; ki < 2; ki++) {
            bf16x8 af[4], bfr[4];
            #pragma unroll
            for (int mi = 0; mi < 4; mi++)
                af[mi] = *reinterpret_cast<const bf16x8*>(&Alds[wm + mi * 16 + l16][ki * 32 + g * 8]);
            #pragma unroll
            for (int ni = 0; ni < 4; ni++)
                bfr[ni] = *reinterpret_cast<const bf16x8*>(&Blds[wn + ni * 16 + l16][ki * 32 + g * 8]);
            #pragma unroll
            for (int mi = 0; mi < 4; mi++)
                #pragma unroll
                for (int ni = 0; ni < 4; ni++)
                    acc[mi][ni] = __builtin_amdgcn_mfma_f32_16x16x32_bf16(af[mi], bfr[ni], acc[mi][ni], 0, 0, 0);
        }
    }

    #pragma unroll
    for (int mi = 0; mi < 4; mi++) {
        #pragma unroll
        for (int ni = 0; ni < 4; ni++) {
            #pragma unroll
            for (int r = 0; r < 4; r++) {
                float v = acc[mi][ni][r];
                int mrow = tm + wm + mi * 16 + g * 4 + r;
                int c    = tn + wn + ni * 16 + l16;
                if (EPI == 0) {
                    int which = c / 768, cc = c - which * 768;
                    int h = cc >> 6, hd = cc & 63;
                    int b = mrow >> 10, n = mrow & 1023;
                    unsigned short bv = f2bf(v);
                    if (which == 0)      q_ws[((b * H_ + h) * N_ + n) * HD_ + hd] = bv;
                    else if (which == 1) k_ws[((b * H_ + h) * N_ + n) * HD_ + hd] = bv;
                    else                 vt_ws[((b * H_ + h) * HD_ + hd) * N_ + n] = bv;
                } else {
                    outf[mrow * 768 + c] = v + bias[c];
                }
            }
        }
    }
}

// ---------------- attention: R11/R14/R17 PASSING kernel, byte-identical ----------------
// FROZEN. Pipeline-variant record: R7/R8/R12/R15/R16 all failed correctness;
// kt-rotation (R18) was neutral. This exact form passed R11/R13/R14/R17.
// Structure: 768 blocks (bh = f%96 XCD-local), 4 waves, per 64-key tile:
// barrier -> cooperative gload_lds K/V stage -> barrier -> swapped QK^T ->
// fixed-shift softmax (p = exp(s-12), exact) -> u32-typed Plds transpose
// (with compiler fences) -> PV -> direct-store epilogue (*8: softmax/SCALE).
__global__ void __launch_bounds__(256, 3)
k_attn(const unsigned short* __restrict__ q_ws,
       const unsigned short* __restrict__ k_ws,
       const unsigned short* __restrict__ vt_ws,
       unsigned short* __restrict__ att_ws) {
    const int f = blockIdx.x;
    const int qt = f / 96;          // 0..7
    const int bh = f - qt * 96;     // 0..95 ; f%8 == bh%8 -> XCD-local K/V
    const int b = bh / H_, h = bh - b * H_;
    const int tid = threadIdx.x;
    const int w = tid >> 6, l = tid & 63;
    const int g = l >> 4, l16 = l & 15;

    const unsigned short* Qp = q_ws + bh * N_ * HD_;
    const unsigned short* Kp = k_ws + bh * N_ * HD_;
    const unsigned short* Vt = vt_ws + bh * HD_ * N_;
    const int qrow0 = qt * 128 + w * 32;   // this wave's 32 q-rows

    __shared__ __align__(16) unsigned short Kst[64][64];
    __shared__ __align__(16) unsigned short Vst[64][64];
    __shared__ __align__(16) unsigned Plds[4][2][16][36];

    const int sr = l >> 3;          // 0..7  (row within 8-row stripe)
    const int sc = (l & 7) * 8;     // 0..56 (col chunk, elems)

    bf16x8 qf[2][2];
    #pragma unroll
    for (int qb = 0; qb < 2; qb++)
        #pragma unroll
        for (int ki = 0; ki < 2; ki++)
            qf[qb][ki] = *reinterpret_cast<const bf16x8*>(
                &Qp[(qrow0 + qb * 16 + l16) * HD_ + ki * 32 + g * 8]);

    f32x4 o[2][4];
    #pragma unroll
    for (int qb = 0; qb < 2; qb++)
        #pragma unroll
        for (int hi = 0; hi < 4; hi++) o[qb][hi] = (f32x4){0.f, 0.f, 0.f, 0.f};
    float lrow[2] = {0.f, 0.f};

    #pragma unroll 1
    for (int kt = 0; kt < 16; kt++) {
        __syncthreads();   // all waves done reading the previous tile
        #pragma unroll
        for (int i = 0; i < 2; i++) {
            int r0 = w * 16 + i * 8;
            GLOAD_LDS16(&Kp[(size_t)(kt * 64 + r0 + sr) * HD_ + sc], &Kst[r0][0]);
            GLOAD_LDS16(&Vt[(size_t)(r0 + sr) * N_ + kt * 64 + sc], &Vst[r0][0]);
        }
        __syncthreads();   // compiler drains vmcnt(0) before s_barrier

        f32x4 st[2][4];
        #pragma unroll
        for (int qb = 0; qb < 2; qb++)
            #pragma unroll
            for (int ni = 0; ni < 4; ni++) st[qb][ni] = (f32x4){0.f, 0.f, 0.f, 0.f};
        #pragma unroll
        for (int ki = 0; ki < 2; ki++) {
            #pragma unroll
            for (int ni = 0; ni < 4; ni++) {
                bf16x8 kf = *reinterpret_cast<const bf16x8*>(
                    &Kst[ni * 16 + l16][ki * 32 + g * 8]);
                st[0][ni] = __builtin_amdgcn_mfma_f32_16x16x32_bf16(kf, qf[0][ki], st[0][ni], 0, 0, 0);
                st[1][ni] = __builtin_amdgcn_mfma_f32_16x16x32_bf16(kf, qf[1][ki], st[1][ni], 0, 0, 0);
            }
        }

        #pragma unroll
        for (int qb = 0; qb < 2; qb++) {
            #pragma unroll
            for (int ni = 0; ni < 4; ni++) {
                float p0 = __expf(st[qb][ni][0] - 12.0f);
                float p1 = __expf(st[qb][ni][1] - 12.0f);
                float p2 = __expf(st[qb][ni][2] - 12.0f);
                float p3 = __expf(st[qb][ni][3] - 12.0f);
                lrow[qb] += (p0 + p1) + (p2 + p3);
                u32x2 pk = (u32x2){cvt_pk_bf16(p0, p1), cvt_pk_bf16(p2, p3)};
                *reinterpret_cast<u32x2*>(&Plds[w][qb][l16][ni * 8 + g * 2]) = pk;
            }
        }

        COMPILER_MEM_FENCE();   // P writes may not sink below the PV reads

        #pragma unroll
        for (int ki2 = 0; ki2 < 2; ki2++) {
            bf16x8 vf[4];
            #pragma unroll
            for (int hi = 0; hi < 4; hi++)
                vf[hi] = *reinterpret_cast<const bf16x8*>(
                    &Vst[hi * 16 + l16][ki2 * 32 + g * 8]);
            #pragma unroll
            for (int qb = 0; qb < 2; qb++) {
                u32x4 praw = *reinterpret_cast<const u32x4*>(
                    &Plds[w][qb][l16][ki2 * 16 + g * 4]);
                bf16x8 pa = __builtin_bit_cast(bf16x8, praw);
                #pragma unroll
                for (int hi = 0; hi < 4; hi++)
                    o[qb][hi] = __builtin_amdgcn_mfma_f32_16x16x32_bf16(pa, vf[hi], o[qb][hi], 0, 0, 0);
            }
        }

        COMPILER_MEM_FENCE();   // next tile's P writes may not hoist above these reads
    }

    #pragma unroll
    for (int qb = 0; qb < 2; qb++) {
        float s0 = lrow[qb];
        s0 += __shfl_xor(s0, 16);
        s0 += __shfl_xor(s0, 32);
        lrow[qb] = s0;
    }

    #pragma unroll
    for (int qb = 0; qb < 2; qb++) {
        float inv[4];
        #pragma unroll
        for (int r = 0; r < 4; r++)
            inv[r] = 8.0f / __shfl(lrow[qb], g * 4 + r);   // *8: softmax/SCALE quirk
        #pragma unroll
        for (int hi = 0; hi < 4; hi++) {
            #pragma unroll
            for (int r = 0; r < 4; r++) {
                float v = o[qb][hi][r] * inv[r];
                int n = qrow0 + qb * 16 + g * 4 + r;
                att_ws[((size_t)(b * N_ + n)) * 768 + h * 64 + hi * 16 + l16] = f2bf(v);
            }
        }
    }
}

// ---------------- launch ----------------

extern "C" void kernel_launch(void* const* d_in, const int* in_sizes, int n_in,
                              void* d_out, int out_size, void* d_ws, size_t ws_size,
                              hipStream_t stream) {
    const float* x      = (const float*)d_in[0];
    const float* w_qkv  = (const float*)d_in[1];
    const float* w_proj = (const float*)d_in[2];
    const float* b_proj = (const float*)d_in[3];
    float* out = (float*)d_out;

    char* ws = (char*)d_ws;
    size_t off = 0;
    auto carve = [&](size_t bytes) {
        void* p = ws + off;
        off += (bytes + 255) & ~(size_t)255;
        return p;
    };
    unsigned short* xb     = (unsigned short*)carve((size_t)M_ * D_ * 2);
    unsigned short* wqkvT  = (unsigned short*)carve((size_t)TRIPLE * D_ * 2);
    unsigned short* wprojT = (unsigned short*)carve((size_t)D_ * D_ * 2);
    unsigned short* q_ws   = (unsigned short*)carve((size_t)B_ * H_ * N_ * HD_ * 2);
    unsigned short* k_ws   = (unsigned short*)carve((size_t)B_ * H_ * N_ * HD_ * 2);
    unsigned short* vt_ws  = (unsigned short*)carve((size_t)B_ * H_ * N_ * HD_ * 2);
    unsigned short* att_ws = (unsigned short*)carve((size_t)M_ * 768 * 2);

    k_cast_bf16<<<2048, 256, 0, stream>>>(x, xb, M_ * D_ / 4);
    // tiled transposes: in [R][C] -> out [C][R]; grid (C/32, R/32), block (32,8)
    k_transpose_bf16<<<dim3(TRIPLE / 32, D_ / 32), dim3(32, 8), 0, stream>>>(w_qkv, wqkvT, D_, TRIPLE);
    k_transpose_bf16<<<dim3(D_ / 32, D_ / 32), dim3(32, 8), 0, stream>>>(w_proj, wprojT, D_, D_);

    // qkv = x @ w_qkv  -> scatter q,k,[v^T]   (2-D grid, tm fastest)
    k_gemm<0><<<dim3(M_ / 128, TRIPLE / 128), 256, 0, stream>>>(
        xb, wqkvT, D_, q_ws, k_ws, vt_ws, nullptr, nullptr);

    // attention (1-D grid; bh fastest for XCD-local K/V)
    k_attn<<<dim3(768), 256, 0, stream>>>(q_ws, k_ws, vt_ws, att_ws);

    // out = att @ w_proj + b   (2-D grid)
    k_gemm<1><<<dim3(M_ / 128, 768 / 128), 256, 0, stream>>>(
        att_ws, wprojT, D_, nullptr, nullptr, nullptr, b_proj, out);
}

// Round 20
// 132.033 us; speedup vs baseline: 1.0827x; 1.0256x over previous
//
#include <hip/hip_runtime.h>
#include <hip/hip_bf16.h>

// Problem constants
#define B_    8
#define N_    1024
#define D_    768
#define H_    12
#define HD_   64
#define TRIPLE 2304   // 3*768
#define M_    8192    // B_*N_

typedef __attribute__((ext_vector_type(8))) short bf16x8;
typedef __attribute__((ext_vector_type(4))) float f32x4;
typedef __attribute__((ext_vector_type(2))) unsigned u32x2;
typedef __attribute__((ext_vector_type(4))) unsigned u32x4;

// f32 -> bf16 (RNE), no NaN expected in this problem
__device__ __forceinline__ unsigned short f2bf(float f) {
    union { float f; unsigned u; } v; v.f = f;
    unsigned r = v.u + 0x7fffu + ((v.u >> 16) & 1u);
    return (unsigned short)(r >> 16);
}

// packed f32x2 -> bf16x2 (lo = a, hi = b); guide-verified gfx950 instruction
__device__ __forceinline__ unsigned cvt_pk_bf16(float a, float b) {
    unsigned r;
    asm("v_cvt_pk_bf16_f32 %0, %1, %2" : "=v"(r) : "v"(a), "v"(b));
    return r;
}

// compiler-level memory fence: no instructions emitted, forbids reordering
#define COMPILER_MEM_FENCE() asm volatile("" ::: "memory")

// async 16B global->LDS (m97 pattern): LDS dest is wave-uniform base + lane*16
#define GLOAD_LDS16(gp, lp)                                                   \
    __builtin_amdgcn_global_load_lds(                                         \
        (const __attribute__((address_space(1))) void*)(gp),                  \
        (__attribute__((address_space(3))) void*)(lp), 16, 0, 0)

// ---------------- fused prep kernel ----------------
// One launch replaces {cast, wqkv-transpose, wproj-transpose} (R20): the three
// regions are disjoint, branches are block-uniform, each body is byte-identical
// to its R19-passing kernel. Partition of the flat 4352-block grid:
//   [0, 2048)          : x f32 -> bf16 cast, grid-stride (stride hardcoded)
//   [2048, 2048+1728)  : w_qkv [768][2304] -> wqkvT [2304][768] tiled transpose
//   [3776, 3776+576)   : w_proj [768][768] -> wprojT [768][768] tiled transpose
#define PREP_CAST_BLOCKS 2048
#define PREP_TQ_BLOCKS   ((TRIPLE / 32) * (D_ / 32))   // 72*24 = 1728
#define PREP_TP_BLOCKS   ((D_ / 32) * (D_ / 32))       // 24*24 = 576
#define PREP_BLOCKS      (PREP_CAST_BLOCKS + PREP_TQ_BLOCKS + PREP_TP_BLOCKS)

__global__ void k_prep(const float* __restrict__ x, unsigned short* __restrict__ xb,
                       const float* __restrict__ w_qkv, unsigned short* __restrict__ wqkvT,
                       const float* __restrict__ w_proj, unsigned short* __restrict__ wprojT) {
    __shared__ float tile[32][33];
    const int bid = blockIdx.x;
    const int tid = threadIdx.x;

    if (bid < PREP_CAST_BLOCKS) {
        // cast: n4 = M_*D_/4 float4 chunks, stride = partition size
        const int n4 = M_ * D_ / 4;
        const int stride = PREP_CAST_BLOCKS * 256;
        for (int i = bid * 256 + tid; i < n4; i += stride) {
            float4 v = reinterpret_cast<const float4*>(x)[i];
            ushort4 o;
            o.x = f2bf(v.x); o.y = f2bf(v.y); o.z = f2bf(v.z); o.w = f2bf(v.w);
            reinterpret_cast<ushort4*>(xb)[i] = o;
        }
        return;
    }

    // tiled transpose branch (body == R19 k_transpose_bf16; block-uniform)
    const float* in; unsigned short* out; int R, C, bx, by;
    if (bid < PREP_CAST_BLOCKS + PREP_TQ_BLOCKS) {
        int id2 = bid - PREP_CAST_BLOCKS;
        in = w_qkv; out = wqkvT; R = D_; C = TRIPLE;
        bx = (id2 % (TRIPLE / 32)) * 32;
        by = (id2 / (TRIPLE / 32)) * 32;
    } else {
        int id3 = bid - PREP_CAST_BLOCKS - PREP_TQ_BLOCKS;
        in = w_proj; out = wprojT; R = D_; C = D_;
        bx = (id3 % (D_ / 32)) * 32;
        by = (id3 / (D_ / 32)) * 32;
    }
    const int tx = tid & 31, ty = tid >> 5;   // (32, 8) layout from flat 256
    #pragma unroll
    for (int j = 0; j < 32; j += 8)
        tile[ty + j][tx] = in[(size_t)(by + ty + j) * C + bx + tx];
    __syncthreads();
    #pragma unroll
    for (int j = 0; j < 32; j += 8)
        out[(size_t)(bx + ty + j) * R + by + tx] = f2bf(tile[tx][ty + j]);
}

// ---------------- GEMM: C = A[M,K] * BT[N,K]^T, bf16 in, f32 acc ----------------
// 128x128 tile, 256 threads (4 waves, 2x2 of 64x64), mfma_f32_16x16x32_bf16.
// m97-style staging: global_load_lds width=16 into LINEAR [128][64] LDS.
// 2-D grid, tm fastest, IN-ORDER k sweep. Measured order-perturbation record:
//   R13 XCD chunk-swizzle: FETCH 25.9->77.5MB, 62->81us. REVERTED.
//   R18 anti-convoy k-rotation: FETCH 25.9->64.9MB, 62->70.7us. REVERTED.
// Rule: at this problem size, temporal phase-alignment across blocks IS the
// cache locality. Do not perturb block/k ordering.
// EPI 0: scatter qkv epilogue. EPI 1: bias + f32 out (projection).
template<int EPI>
__global__ void k_gemm(const unsigned short* __restrict__ A,
                       const unsigned short* __restrict__ BT,
                       int K,
                       unsigned short* __restrict__ q_ws,
                       unsigned short* __restrict__ k_ws,
                       unsigned short* __restrict__ vt_ws,
                       const float* __restrict__ bias,
                       float* __restrict__ outf) {
    const int tm = blockIdx.x * 128;
    const int tn = blockIdx.y * 128;
    const int tid = threadIdx.x;
    const int w = tid >> 6, l = tid & 63;
    const int g = l >> 4, l16 = l & 15;
    const int wm = (w >> 1) * 64, wn = (w & 1) * 64;

    __shared__ __align__(16) unsigned short Alds[128][64];
    __shared__ __align__(16) unsigned short Blds[128][64];

    const int srow = (l >> 3);          // 0..7
    const int scol = (l & 7) * 8;       // 0..56

    f32x4 acc[4][4];
    for (int mi = 0; mi < 4; mi++)
        for (int ni = 0; ni < 4; ni++)
            acc[mi][ni] = (f32x4){0.f, 0.f, 0.f, 0.f};

    for (int k0 = 0; k0 < K; k0 += 64) {
        __syncthreads();
        #pragma unroll
        for (int i = 0; i < 4; i++) {
            int r0 = (w * 4 + i) * 8;
            GLOAD_LDS16(&A[(size_t)(tm + r0 + srow) * K + k0 + scol], &Alds[r0][0]);
            GLOAD_LDS16(&BT[(size_t)(tn + r0 + srow) * K + k0 + scol], &Blds[r0][0]);
        }
        __syncthreads();

        #pragma unroll
        for (int ki = 0; ki < 2; ki++) {
            bf16x8 af[4], bfr[4];
            #pragma unroll
            for (int mi = 0; mi < 4; mi++)
                af[mi] = *reinterpret_cast<const bf16x8*>(&Alds[wm + mi * 16 + l16][ki * 32 + g * 8]);
            #pragma unroll
            for (int ni = 0; ni < 4; ni++)
                bfr[ni] = *reinterpret_cast<const bf16x8*>(&Blds[wn + ni * 16 + l16][ki * 32 + g * 8]);
            #pragma unroll
            for (int mi = 0; mi < 4; mi++)
                #pragma unroll
                for (int ni = 0; ni < 4; ni++)
                    acc[mi][ni] = __builtin_amdgcn_mfma_f32_16x16x32_bf16(af[mi], bfr[ni], acc[mi][ni], 0, 0, 0);
        }
    }

    #pragma unroll
    for (int mi = 0; mi < 4; mi++) {
        #pragma unroll
        for (int ni = 0; ni < 4; ni++) {
            #pragma unroll
            for (int r = 0; r < 4; r++) {
                float v = acc[mi][ni][r];
                int mrow = tm + wm + mi * 16 + g * 4 + r;
                int c    = tn + wn + ni * 16 + l16;
                if (EPI == 0) {
                    int which = c / 768, cc = c - which * 768;
                    int h = cc >> 6, hd = cc & 63;
                    int b = mrow >> 10, n = mrow & 1023;
                    unsigned short bv = f2bf(v);
                    if (which == 0)      q_ws[((b * H_ + h) * N_ + n) * HD_ + hd] = bv;
                    else if (which == 1) k_ws[((b * H_ + h) * N_ + n) * HD_ + hd] = bv;
                    else                 vt_ws[((b * H_ + h) * HD_ + hd) * N_ + n] = bv;
                } else {
                    outf[mrow * 768 + c] = v + bias[c];
                }
            }
        }
    }
}

// ---------------- attention: R11/R14/R17/R19 PASSING kernel, byte-identical ----------------
// FROZEN. Pipeline-variant record: R7/R8/R12/R15/R16 all failed correctness;
// kt-rotation (R18) neutral-to-negative. This exact form passed R11/R13/R14/R17/R19.
__global__ void __launch_bounds__(256, 3)
k_attn(const unsigned short* __restrict__ q_ws,
       const unsigned short* __restrict__ k_ws,
       const unsigned short* __restrict__ vt_ws,
       unsigned short* __restrict__ att_ws) {
    const int f = blockIdx.x;
    const int qt = f / 96;          // 0..7
    const int bh = f - qt * 96;     // 0..95 ; f%8 == bh%8 -> XCD-local K/V
    const int b = bh / H_, h = bh - b * H_;
    const int tid = threadIdx.x;
    const int w = tid >> 6, l = tid & 63;
    const int g = l >> 4, l16 = l & 15;

    const unsigned short* Qp = q_ws + bh * N_ * HD_;
    const unsigned short* Kp = k_ws + bh * N_ * HD_;
    const unsigned short* Vt = vt_ws + bh * HD_ * N_;
    const int qrow0 = qt * 128 + w * 32;   // this wave's 32 q-rows

    __shared__ __align__(16) unsigned short Kst[64][64];
    __shared__ __align__(16) unsigned short Vst[64][64];
    __shared__ __align__(16) unsigned Plds[4][2][16][36];

    const int sr = l >> 3;          // 0..7  (row within 8-row stripe)
    const int sc = (l & 7) * 8;     // 0..56 (col chunk, elems)

    bf16x8 qf[2][2];
    #pragma unroll
    for (int qb = 0; qb < 2; qb++)
        #pragma unroll
        for (int ki = 0; ki < 2; ki++)
            qf[qb][ki] = *reinterpret_cast<const bf16x8*>(
                &Qp[(qrow0 + qb * 16 + l16) * HD_ + ki * 32 + g * 8]);

    f32x4 o[2][4];
    #pragma unroll
    for (int qb = 0; qb < 2; qb++)
        #pragma unroll
        for (int hi = 0; hi < 4; hi++) o[qb][hi] = (f32x4){0.f, 0.f, 0.f, 0.f};
    float lrow[2] = {0.f, 0.f};

    #pragma unroll 1
    for (int kt = 0; kt < 16; kt++) {
        __syncthreads();   // all waves done reading the previous tile
        #pragma unroll
        for (int i = 0; i < 2; i++) {
            int r0 = w * 16 + i * 8;
            GLOAD_LDS16(&Kp[(size_t)(kt * 64 + r0 + sr) * HD_ + sc], &Kst[r0][0]);
            GLOAD_LDS16(&Vt[(size_t)(r0 + sr) * N_ + kt * 64 + sc], &Vst[r0][0]);
        }
        __syncthreads();   // compiler drains vmcnt(0) before s_barrier

        f32x4 st[2][4];
        #pragma unroll
        for (int qb = 0; qb < 2; qb++)
            #pragma unroll
            for (int ni = 0; ni < 4; ni++) st[qb][ni] = (f32x4){0.f, 0.f, 0.f, 0.f};
        #pragma unroll
        for (int ki = 0; ki < 2; ki++) {
            #pragma unroll
            for (int ni = 0; ni < 4; ni++) {
                bf16x8 kf = *reinterpret_cast<const bf16x8*>(
                    &Kst[ni * 16 + l16][ki * 32 + g * 8]);
                st[0][ni] = __builtin_amdgcn_mfma_f32_16x16x32_bf16(kf, qf[0][ki], st[0][ni], 0, 0, 0);
                st[1][ni] = __builtin_amdgcn_mfma_f32_16x16x32_bf16(kf, qf[1][ki], st[1][ni], 0, 0, 0);
            }
        }

        #pragma unroll
        for (int qb = 0; qb < 2; qb++) {
            #pragma unroll
            for (int ni = 0; ni < 4; ni++) {
                float p0 = __expf(st[qb][ni][0] - 12.0f);
                float p1 = __expf(st[qb][ni][1] - 12.0f);
                float p2 = __expf(st[qb][ni][2] - 12.0f);
                float p3 = __expf(st[qb][ni][3] - 12.0f);
                lrow[qb] += (p0 + p1) + (p2 + p3);
                u32x2 pk = (u32x2){cvt_pk_bf16(p0, p1), cvt_pk_bf16(p2, p3)};
                *reinterpret_cast<u32x2*>(&Plds[w][qb][l16][ni * 8 + g * 2]) = pk;
            }
        }

        COMPILER_MEM_FENCE();   // P writes may not sink below the PV reads

        #pragma unroll
        for (int ki2 = 0; ki2 < 2; ki2++) {
            bf16x8 vf[4];
            #pragma unroll
            for (int hi = 0; hi < 4; hi++)
                vf[hi] = *reinterpret_cast<const bf16x8*>(
                    &Vst[hi * 16 + l16][ki2 * 32 + g * 8]);
            #pragma unroll
            for (int qb = 0; qb < 2; qb++) {
                u32x4 praw = *reinterpret_cast<const u32x4*>(
                    &Plds[w][qb][l16][ki2 * 16 + g * 4]);
                bf16x8 pa = __builtin_bit_cast(bf16x8, praw);
                #pragma unroll
                for (int hi = 0; hi < 4; hi++)
                    o[qb][hi] = __builtin_amdgcn_mfma_f32_16x16x32_bf16(pa, vf[hi], o[qb][hi], 0, 0, 0);
            }
        }

        COMPILER_MEM_FENCE();   // next tile's P writes may not hoist above these reads
    }

    #pragma unroll
    for (int qb = 0; qb < 2; qb++) {
        float s0 = lrow[qb];
        s0 += __shfl_xor(s0, 16);
        s0 += __shfl_xor(s0, 32);
        lrow[qb] = s0;
    }

    #pragma unroll
    for (int qb = 0; qb < 2; qb++) {
        float inv[4];
        #pragma unroll
        for (int r = 0; r < 4; r++)
            inv[r] = 8.0f / __shfl(lrow[qb], g * 4 + r);   // *8: softmax/SCALE quirk
        #pragma unroll
        for (int hi = 0; hi < 4; hi++) {
            #pragma unroll
            for (int r = 0; r < 4; r++) {
                float v = o[qb][hi][r] * inv[r];
                int n = qrow0 + qb * 16 + g * 4 + r;
                att_ws[((size_t)(b * N_ + n)) * 768 + h * 64 + hi * 16 + l16] = f2bf(v);
            }
        }
    }
}

// ---------------- launch ----------------

extern "C" void kernel_launch(void* const* d_in, const int* in_sizes, int n_in,
                              void* d_out, int out_size, void* d_ws, size_t ws_size,
                              hipStream_t stream) {
    const float* x      = (const float*)d_in[0];
    const float* w_qkv  = (const float*)d_in[1];
    const float* w_proj = (const float*)d_in[2];
    const float* b_proj = (const float*)d_in[3];
    float* out = (float*)d_out;

    char* ws = (char*)d_ws;
    size_t off = 0;
    auto carve = [&](size_t bytes) {
        void* p = ws + off;
        off += (bytes + 255) & ~(size_t)255;
        return p;
    };
    unsigned short* xb     = (unsigned short*)carve((size_t)M_ * D_ * 2);
    unsigned short* wqkvT  = (unsigned short*)carve((size_t)TRIPLE * D_ * 2);
    unsigned short* wprojT = (unsigned short*)carve((size_t)D_ * D_ * 2);
    unsigned short* q_ws   = (unsigned short*)carve((size_t)B_ * H_ * N_ * HD_ * 2);
    unsigned short* k_ws   = (unsigned short*)carve((size_t)B_ * H_ * N_ * HD_ * 2);
    unsigned short* vt_ws  = (unsigned short*)carve((size_t)B_ * H_ * N_ * HD_ * 2);
    unsigned short* att_ws = (unsigned short*)carve((size_t)M_ * 768 * 2);

    // fused preps: cast + both transposes in ONE launch (R20)
    k_prep<<<dim3(PREP_BLOCKS), 256, 0, stream>>>(x, xb, w_qkv, wqkvT, w_proj, wprojT);

    // qkv = x @ w_qkv  -> scatter q,k,[v^T]   (2-D grid, tm fastest)
    k_gemm<0><<<dim3(M_ / 128, TRIPLE / 128), 256, 0, stream>>>(
        xb, wqkvT, D_, q_ws, k_ws, vt_ws, nullptr, nullptr);

    // attention (1-D grid; bh fastest for XCD-local K/V)
    k_attn<<<dim3(768), 256, 0, stream>>>(q_ws, k_ws, vt_ws, att_ws);

    // out = att @ w_proj + b   (2-D grid)
    k_gemm<1><<<dim3(M_ / 128, 768 / 128), 256, 0, stream>>>(
        att_ws, wprojT, D_, nullptr, nullptr, nullptr, b_proj, out);
}